// Round 8
// baseline (191.173 us; speedup 1.0000x reference)
//
#include <hip/hip_runtime.h>

// PlateYoloBlock: (32,13,256,256) fp32 -> (32,65536,13) fp32
// out[b][y*256+x][c]:
//   c=0: (sigmoid(v)+x)*8   c=1: (sigmoid(v)+y)*8
//   c=2,3: exp(v)*8         c=4..11: v*8          c=12: sigmoid(v)
//
// v7: L1-BYPASS READ PROBE. Four read machineries (scalar, dwordx4,
// DMA-to-LDS, pipelined) all pin at ~2.5 TB/s HBM while write-only fill
// does 6.6 and copy does 6.3 total. Best-fit theory: per-CU outstanding
// read-line cap in the L1/TA miss tracker (~40 lines x 128B x 256 CU /
// 400ns ~= 3.3 TB/s app-level = measured). Device-scope loads (sc0 sc1)
// bypass L1 and track misses in the per-XCD L2's much deeper queues.
// Body is v2 verbatim (65.6us clean A/B baseline); ONLY the phase-A load
// instruction changes.

#define NB      32
#define NC      13
#define HW      65536     // 256*256 positions per batch
#define WIDTH   256
#define TILE    1024      // positions per block
#define THREADS 256
#define PPT     4         // positions per thread
#define NBLOCKS ((NB * HW) / TILE)   // 2048

typedef float v4f __attribute__((ext_vector_type(4)));

__device__ __forceinline__ float sigmoidf_(float x) {
    return 1.0f / (1.0f + __expf(-x));
}

__global__ __launch_bounds__(THREADS) void plate_yolo_kernel(
        const float* __restrict__ in, float* __restrict__ out) {
    __shared__ float lds[TILE * NC];   // 53,248 B -> 3 blocks/CU

    const int tid = threadIdx.x;
    const long long s0 = (long long)blockIdx.x * TILE;   // global spatial base
    const int b = (int)(s0 >> 16);                       // 65536 positions/batch
    const int posBase = (int)(s0 & (HW - 1));
    const float* __restrict__ inB = in + (long long)b * NC * HW + posBase;

    const int p0   = tid * PPT;          // 4 consecutive positions
    const int pos0 = posBase + p0;
    const float fx0 = (float)(pos0 & (WIDTH - 1));  // row not crossed in a quad
    const float fy  = (float)(pos0 >> 8);

    // Phase A: 13 device-scope (L1-bypassing) dwordx4 loads, all issued
    // before any use. sc0 sc1 -> miss tracking moves from L1 MSHRs to the
    // per-XCD L2. Explicit vmcnt(0) + sched_barrier(0) before consumption
    // (rule #18: compiler may hoist VALU past inline-asm waitcnt).
    v4f v[NC];
    #pragma unroll
    for (int c = 0; c < NC; ++c) {
        const v4f* ap = (const v4f*)(inB + c * HW + p0);
        asm volatile("global_load_dwordx4 %0, %1, off sc0 sc1"
                     : "=v"(v[c]) : "v"(ap));
    }
    asm volatile("s_waitcnt vmcnt(0)" ::: "memory");
    __builtin_amdgcn_sched_barrier(0);

    // Phase B: pointwise math into output-layout register block (v2 verbatim).
    float res[PPT * NC];                 // res[q*13 + c], all static indices
    #pragma unroll
    for (int c = 0; c < NC; ++c) {
        #pragma unroll
        for (int q = 0; q < PPT; ++q) {
            const float x = v[c][q];
            float r;
            if (c == 0)                 r = (sigmoidf_(x) + (fx0 + (float)q)) * 8.0f;
            else if (c == 1)            r = (sigmoidf_(x) + fy) * 8.0f;
            else if (c == 2 || c == 3)  r = __expf(x) * 8.0f;
            else if (c == 12)           r = sigmoidf_(x);
            else                        r = x * 8.0f;
            res[q * NC + c] = r;
        }
    }

    // Phase C: 13 ds_write_b128 into the thread's contiguous 52-float region
    // (v2 verbatim; measured 1.4M conflict cycles, fully masked by memory).
    v4f* __restrict__ ldsT = (v4f*)(lds + p0 * NC);
    #pragma unroll
    for (int j = 0; j < NC; ++j) {
        v4f w;
        w[0] = res[4*j + 0]; w[1] = res[4*j + 1];
        w[2] = res[4*j + 2]; w[3] = res[4*j + 3];
        ldsT[j] = w;
    }
    __syncthreads();

    // Phase D: contiguous float4 copy-out (v2 verbatim).
    const v4f* __restrict__ src = (const v4f*)lds;
    v4f* __restrict__ dst = (v4f*)(out + s0 * NC);
    #pragma unroll
    for (int j = 0; j < NC; ++j) {
        dst[tid + j * THREADS] = src[tid + j * THREADS];
    }
}

extern "C" void kernel_launch(void* const* d_in, const int* in_sizes, int n_in,
                              void* d_out, int out_size, void* d_ws, size_t ws_size,
                              hipStream_t stream) {
    const float* in = (const float*)d_in[0];
    float* out = (float*)d_out;
    plate_yolo_kernel<<<NBLOCKS, THREADS, 0, stream>>>(in, out);
}

// Round 9
// 184.715 us; speedup vs baseline: 1.0350x; 1.0350x over previous
//
#include <hip/hip_runtime.h>

// PlateYoloBlock: (32,13,256,256) fp32 -> (32,65536,13) fp32
// out[b][y*256+x][c]:
//   c=0: (sigmoid(v)+x)*8   c=1: (sigmoid(v)+y)*8
//   c=2,3: exp(v)*8         c=4..11: v*8          c=12: sigmoid(v)
//
// v8: NON-TEMPORAL LOAD PROBE. Every variant shows FETCH_SIZE = 53 MB =
// 49% of input: half the reads hit the memory-side Infinity Cache, half
// miss — so the HBM read stream is a line-granular SIEVE (fetch one line,
// skip one), fragmenting DRAM row visits. Dense-read copy does 6.3 TB/s;
// our fragmented mix does 2.5. nt loads (LLC no-allocate) stop the input
// from re-allocating in the MALL -> steady-state reads become one dense
// 109 MB HBM stream. FETCH_SIZE gives an unambiguous readout:
//   FETCH ~107MB + faster  -> fragmentation confirmed
//   FETCH ~107MB + slower  -> total-HBM-rate wall; current 65us is optimal
//   FETCH unchanged        -> nt can't reach MALL; lever inaccessible
// Body is v2 verbatim; ONLY the load intrinsic changes.

#define NB      32
#define NC      13
#define HW      65536     // 256*256 positions per batch
#define WIDTH   256
#define TILE    1024      // positions per block
#define THREADS 256
#define PPT     4         // positions per thread
#define NBLOCKS ((NB * HW) / TILE)   // 2048

typedef float v4f __attribute__((ext_vector_type(4)));

__device__ __forceinline__ float sigmoidf_(float x) {
    return 1.0f / (1.0f + __expf(-x));
}

__global__ __launch_bounds__(THREADS) void plate_yolo_kernel(
        const float* __restrict__ in, float* __restrict__ out) {
    __shared__ float lds[TILE * NC];   // 53,248 B -> 3 blocks/CU

    const int tid = threadIdx.x;
    const long long s0 = (long long)blockIdx.x * TILE;   // global spatial base
    const int b = (int)(s0 >> 16);                       // 65536 positions/batch
    const int posBase = (int)(s0 & (HW - 1));
    const float* __restrict__ inB = in + (long long)b * NC * HW + posBase;

    const int p0   = tid * PPT;          // 4 consecutive positions
    const int pos0 = posBase + p0;
    const float fx0 = (float)(pos0 & (WIDTH - 1));  // row not crossed in a quad
    const float fy  = (float)(pos0 >> 8);

    // Phase A: 13 NON-TEMPORAL dwordx4 loads (nt = LLC no-allocate),
    // all issued before any use.
    v4f v[NC];
    #pragma unroll
    for (int c = 0; c < NC; ++c) {
        v[c] = __builtin_nontemporal_load((const v4f*)(inB + c * HW + p0));
    }

    // Phase B: pointwise math into output-layout register block (v2 verbatim).
    float res[PPT * NC];                 // res[q*13 + c], all static indices
    #pragma unroll
    for (int c = 0; c < NC; ++c) {
        #pragma unroll
        for (int q = 0; q < PPT; ++q) {
            const float x = v[c][q];
            float r;
            if (c == 0)                 r = (sigmoidf_(x) + (fx0 + (float)q)) * 8.0f;
            else if (c == 1)            r = (sigmoidf_(x) + fy) * 8.0f;
            else if (c == 2 || c == 3)  r = __expf(x) * 8.0f;
            else if (c == 12)           r = sigmoidf_(x);
            else                        r = x * 8.0f;
            res[q * NC + c] = r;
        }
    }

    // Phase C: 13 ds_write_b128 into the thread's contiguous 52-float region
    // (v2 verbatim; 1.4M conflict cycles, fully masked by memory).
    v4f* __restrict__ ldsT = (v4f*)(lds + p0 * NC);
    #pragma unroll
    for (int j = 0; j < NC; ++j) {
        v4f w;
        w[0] = res[4*j + 0]; w[1] = res[4*j + 1];
        w[2] = res[4*j + 2]; w[3] = res[4*j + 3];
        ldsT[j] = w;
    }
    __syncthreads();

    // Phase D: contiguous float4 copy-out (v2 verbatim).
    const v4f* __restrict__ src = (const v4f*)lds;
    v4f* __restrict__ dst = (v4f*)(out + s0 * NC);
    #pragma unroll
    for (int j = 0; j < NC; ++j) {
        dst[tid + j * THREADS] = src[tid + j * THREADS];
    }
}

extern "C" void kernel_launch(void* const* d_in, const int* in_sizes, int n_in,
                              void* d_out, int out_size, void* d_ws, size_t ws_size,
                              hipStream_t stream) {
    const float* in = (const float*)d_in[0];
    float* out = (float*)d_out;
    plate_yolo_kernel<<<NBLOCKS, THREADS, 0, stream>>>(in, out);
}